// Round 5
// baseline (450.524 us; speedup 1.0000x reference)
//
#include <hip/hip_runtime.h>
#include <math.h>

// ---------------------------------------------------------------------------
// AttnBlock: per-edge radial-MLP attention logits + segment softmax over dst.
//
// R5 structure (3 stream ops):
//   memset ssum[N]=0 (double)
//   K1 edge:  dot[e] -> d_out (fp32), atomicAdd ssum[v[e]] += exp_wide(dot)
//   K2 norm:  d_out[e] = (float)( exp_wide(dot) / ssum[v[e]] )
//
// KEY CHANGE vs R4: the 4 radial MLPs run in a ROLLED loop (unroll-disable)
// with wave-uniform `if (i==k)` epilogue branches. R3/R4 evidence: duration
// identical (180 vs 184 us) while waves x codesize was identical (750 MB of
// I-stream); VALUBusy pinned ~44% regardless of ILP/occupancy -> the
// fully-unrolled ~30-60 KB body overflows the 32 KB I-cache and every wave
// streams code from L2. Rolled body ~7 KB stays resident.
//
// exp_wide: fp32 exp2 + bit-built 2^k scaling into double (R3-verified f64
// range semantics needed; fp32 exp overflowed in the tails).
// ---------------------------------------------------------------------------

#define TPB 256

typedef float f2 __attribute__((ext_vector_type(2)));
typedef int i2 __attribute__((ext_vector_type(2)));

static __device__ __forceinline__ f2 fma2(f2 a, f2 b, f2 c) {
    return __builtin_elementwise_fma(a, b, c);
}
static __device__ __forceinline__ f2 splat(float x) {
    f2 r;
    r.x = x;
    r.y = x;
    return r;
}
static __device__ __forceinline__ float get16(const f2* h, int c) {
    return (c & 1) ? h[c >> 1].y : h[c >> 1].x;
}

// exp(d) with f64-exp range semantics: result = 2^(d*log2e) as double.
static __device__ __forceinline__ double exp_wide(float d) {
    d = fminf(fmaxf(d, -1400.f), 1400.f);
    const float t = d * 1.44269504088896340736f;  // log2(e)
    const float k = rintf(t);
    const float p = exp2f(t - k);  // v_exp_f32, frac in [-0.5,0.5]
    const int ik = (int)k;         // |ik| <= 2020
    const int k1 = ik >> 1;
    const int k2 = ik - k1;        // k1+k2=ik, each in [-1010,1010]
    const double s1 = __hiloint2double((k1 + 1023) << 20, 0);  // 2^k1
    const double s2 = __hiloint2double((k2 + 1023) << 20, 0);  // 2^k2
    return ((double)p * s1) * s2;
}

// LayerNorm(16) + ReLU over h[8] (packed pairs). g/be f2-aligned.
static __device__ __forceinline__ void ln_relu16(f2* h, const float* __restrict__ g,
                                                 const float* __restrict__ be) {
    const f2* g2 = (const f2*)g;
    const f2* be2 = (const f2*)be;
    f2 s = h[0] + h[1] + h[2] + h[3] + h[4] + h[5] + h[6] + h[7];
    const float mu = (s.x + s.y) * 0.0625f;
    const f2 mu2 = splat(mu);
    f2 vs = splat(0.f);
#pragma unroll
    for (int i = 0; i < 8; ++i) {
        f2 d = h[i] - mu2;
        vs = fma2(d, d, vs);
    }
    const float var = (vs.x + vs.y) * 0.0625f;
    const f2 r2 = splat(rsqrtf(var + 1e-5f));
    const f2 zero = splat(0.f);
#pragma unroll
    for (int i = 0; i < 8; ++i) {
        f2 t = (h[i] - mu2) * r2;
        h[i] = __builtin_elementwise_max(fma2(t, g2[i], be2[i]), zero);
    }
}

__global__ __launch_bounds__(TPB, 4) void edge_kernel(
    const float* __restrict__ f0, const float* __restrict__ f1,
    const float* __restrict__ dist, const int* __restrict__ u,
    const int* __restrict__ v, const float* __restrict__ wq,
    const float* __restrict__ wj00, const float* __restrict__ wj01,
    const float* __restrict__ wj10, const float* __restrict__ wj11,
    const float* __restrict__ rW1, const float* __restrict__ rb1,
    const float* __restrict__ g1, const float* __restrict__ be1,
    const float* __restrict__ rW2, const float* __restrict__ rb2,
    const float* __restrict__ g2, const float* __restrict__ be2,
    const float* __restrict__ W3_00, const float* __restrict__ b3_00,
    const float* __restrict__ W3_01, const float* __restrict__ b3_01,
    const float* __restrict__ W3_10, const float* __restrict__ b3_10,
    const float* __restrict__ W3_11, const float* __restrict__ b3_11,
    float* __restrict__ out, double* __restrict__ ssum, int E) {
    const int e = blockIdx.x * blockDim.x + threadIdx.x;
    if (e >= E) return;

    const int uu = __builtin_nontemporal_load(u + e);
    const int vv = v[e];

    const float f0u0 = f0[uu * 2 + 0];
    const float f0u1 = f0[uu * 2 + 1];
    const float f0v0 = f0[vv * 2 + 0];
    const float f0v1 = f0[vv * 2 + 1];
    float f1v[2][3];
#pragma unroll
    for (int i = 0; i < 2; ++i)
#pragma unroll
        for (int m = 0; m < 3; ++m) f1v[i][m] = f1[vv * 6 + i * 3 + m];

    const float vec0 = f0u0 * f0v0;
    const float vec1 = f0u1 * f0v1;
    const float vec2 = __builtin_nontemporal_load(dist + e);

    float acc0[2] = {0.f, 0.f};
    float acc1[2][3] = {{0.f, 0.f, 0.f}, {0.f, 0.f, 0.f}};

    // ---- rolled loop over the 4 radial MLPs (wave-uniform control flow) ----
#pragma clang loop unroll(disable)
    for (int i = 0; i < 4; ++i) {
        const float* W1 = rW1 + i * 48;
        const float* b1 = rb1 + i * 16;
        const float* g1i = g1 + i * 16;
        const float* be1i = be1 + i * 16;
        const float* W2 = rW2 + i * 256;
        const float* b2 = rb2 + i * 16;
        const float* g2i = g2 + i * 16;
        const float* be2i = be2 + i * 16;

        // layer1: 3 -> 16
        f2 h[8];
        {
            const f2* W1r0 = (const f2*)W1;
            const f2* W1r1 = (const f2*)(W1 + 16);
            const f2* W1r2 = (const f2*)(W1 + 32);
            const f2* b1v = (const f2*)b1;
            const f2 a = splat(vec0), b = splat(vec1), c = splat(vec2);
#pragma unroll
            for (int j = 0; j < 8; ++j)
                h[j] = fma2(a, W1r0[j],
                            fma2(b, W1r1[j], fma2(c, W1r2[j], b1v[j])));
        }
        ln_relu16(h, g1i, be1i);

        // layer2: 16 -> 16
        f2 h2[8];
        {
            const f2* b2v = (const f2*)b2;
#pragma unroll
            for (int j = 0; j < 8; ++j) h2[j] = b2v[j];
#pragma unroll
            for (int c = 0; c < 16; ++c) {
                const f2 hc = splat(get16(h, c));
                const f2* row = (const f2*)(W2 + c * 16);
#pragma unroll
                for (int j = 0; j < 8; ++j) h2[j] = fma2(hc, row[j], h2[j]);
            }
        }
        ln_relu16(h2, g2i, be2i);

        // layer3 + epilogue (wave-uniform branches on i)
        if (i == 3) {
            // OUT=12, per j-row consumed immediately with wj11
#pragma unroll
            for (int j = 0; j < 3; ++j) {
                f2 p0 = *(const f2*)(b3_11 + j * 4);
                f2 p1 = *(const f2*)(b3_11 + j * 4 + 2);
#pragma unroll
                for (int c = 0; c < 16; ++c) {
                    const f2 hc = splat(get16(h2, c));
                    p0 = fma2(hc, *(const f2*)(W3_11 + c * 12 + j * 4), p0);
                    p1 = fma2(hc, *(const f2*)(W3_11 + c * 12 + j * 4 + 2), p1);
                }
#pragma unroll
                for (int m = 0; m < 3; ++m) {
                    const float w0 = __builtin_nontemporal_load(
                        wj11 + e * 27 + j * 9 + m * 3 + 0);
                    const float w1 = __builtin_nontemporal_load(
                        wj11 + e * 27 + j * 9 + m * 3 + 1);
                    const float w2 = __builtin_nontemporal_load(
                        wj11 + e * 27 + j * 9 + m * 3 + 2);
                    const float B0 =
                        w0 * f1v[0][0] + w1 * f1v[0][1] + w2 * f1v[0][2];
                    const float B1 =
                        w0 * f1v[1][0] + w1 * f1v[1][1] + w2 * f1v[1][2];
                    acc1[0][m] += p0.x * B0 + p0.y * B1;
                    acc1[1][m] += p1.x * B0 + p1.y * B1;
                }
            }
        } else {
            const float* W3p;
            const float* b3p;
            if (i == 0) {
                W3p = W3_00;
                b3p = b3_00;
            } else if (i == 1) {
                W3p = W3_01;
                b3p = b3_01;
            } else {
                W3p = W3_10;
                b3p = b3_10;
            }
            f2 p0 = *(const f2*)(b3p);
            f2 p1 = *(const f2*)(b3p + 2);
#pragma unroll
            for (int c = 0; c < 16; ++c) {
                const f2 hc = splat(get16(h2, c));
                p0 = fma2(hc, *(const f2*)(W3p + c * 4), p0);
                p1 = fma2(hc, *(const f2*)(W3p + c * 4 + 2), p1);
            }
            if (i == 0) {
                const float w = __builtin_nontemporal_load(wj00 + e);
                acc0[0] += w * (p0.x * f0v0 + p0.y * f0v1);
                acc0[1] += w * (p1.x * f0v0 + p1.y * f0v1);
            } else if (i == 1) {
                const float w0 = __builtin_nontemporal_load(wj01 + e * 3 + 0);
                const float w1 = __builtin_nontemporal_load(wj01 + e * 3 + 1);
                const float w2 = __builtin_nontemporal_load(wj01 + e * 3 + 2);
                const float s0 =
                    w0 * f1v[0][0] + w1 * f1v[0][1] + w2 * f1v[0][2];
                const float s1 =
                    w0 * f1v[1][0] + w1 * f1v[1][1] + w2 * f1v[1][2];
                acc0[0] += p0.x * s0 + p0.y * s1;
                acc0[1] += p1.x * s0 + p1.y * s1;
            } else {
                const float t0 = p0.x * f0v0 + p0.y * f0v1;
                const float t1 = p1.x * f0v0 + p1.y * f0v1;
#pragma unroll
                for (int m = 0; m < 3; ++m) {
                    const float w =
                        __builtin_nontemporal_load(wj10 + e * 3 + m);
                    acc1[0][m] += w * t0;
                    acc1[1][m] += w * t1;
                }
            }
        }
    }

    // ---- q[v] . k_feat ----  wq[d][o][i] = wq[d*4+o*2+i]
    float dot = 0.f;
    {
        const float q00 = wq[0] * f0v0 + wq[1] * f0v1;
        const float q01 = wq[2] * f0v0 + wq[3] * f0v1;
        dot += q00 * acc0[0] + q01 * acc0[1];
#pragma unroll
        for (int m = 0; m < 3; ++m) {
            const float q1m0 = wq[4] * f1v[0][m] + wq[5] * f1v[1][m];
            const float q1m1 = wq[6] * f1v[0][m] + wq[7] * f1v[1][m];
            dot += q1m0 * acc1[0][m] + q1m1 * acc1[1][m];
        }
    }

    __builtin_nontemporal_store(dot, out + e);
    atomicAdd(&ssum[vv], exp_wide(dot));
}

__global__ void norm_kernel(float* __restrict__ out, const int* __restrict__ v,
                            const double* __restrict__ ssum, int E) {
    const int t = blockIdx.x * blockDim.x + threadIdx.x;
    const int e0 = t * 2;
    if (e0 >= E) return;
    if (e0 + 1 < E) {
        const f2 dv = *((const f2*)out + t);
        const i2 vv = *((const i2*)v + t);
        const double s0 = ssum[vv.x];
        const double s1 = ssum[vv.y];
        f2 r;
        r.x = (float)(exp_wide(dv.x) / s0);
        r.y = (float)(exp_wide(dv.y) / s1);
        __builtin_nontemporal_store(r, (f2*)out + t);
    } else {
        out[e0] = (float)(exp_wide(out[e0]) / ssum[v[e0]]);
    }
}

extern "C" void kernel_launch(void* const* d_in, const int* in_sizes, int n_in,
                              void* d_out, int out_size, void* d_ws,
                              size_t ws_size, hipStream_t stream) {
    const float* f0 = (const float*)d_in[0];
    const float* f1 = (const float*)d_in[1];
    const float* dist = (const float*)d_in[2];
    const int* u = (const int*)d_in[3];
    const int* v = (const int*)d_in[4];
    const float* wq = (const float*)d_in[5];
    const float* wj00 = (const float*)d_in[6];
    const float* wj01 = (const float*)d_in[7];
    const float* wj10 = (const float*)d_in[8];
    const float* wj11 = (const float*)d_in[9];
    const float* rW1 = (const float*)d_in[10];
    const float* rb1 = (const float*)d_in[11];
    const float* g1 = (const float*)d_in[12];
    const float* be1 = (const float*)d_in[13];
    const float* rW2 = (const float*)d_in[14];
    const float* rb2 = (const float*)d_in[15];
    const float* g2 = (const float*)d_in[16];
    const float* be2 = (const float*)d_in[17];
    const float* W3_00 = (const float*)d_in[18];
    const float* b3_00 = (const float*)d_in[19];
    const float* W3_01 = (const float*)d_in[20];
    const float* b3_01 = (const float*)d_in[21];
    const float* W3_10 = (const float*)d_in[22];
    const float* b3_10 = (const float*)d_in[23];
    const float* W3_11 = (const float*)d_in[24];
    const float* b3_11 = (const float*)d_in[25];

    const int N = in_sizes[0] / 2;  // f0 is [N,2,1]
    const int E = in_sizes[2];      // dist is [E]

    double* ssum = (double*)d_ws;
    float* out = (float*)d_out;

    const int ge = (E + TPB - 1) / TPB;
    const int gp = ((E + 1) / 2 + TPB - 1) / TPB;

    hipMemsetAsync(ssum, 0, (size_t)N * sizeof(double), stream);
    edge_kernel<<<ge, TPB, 0, stream>>>(
        f0, f1, dist, u, v, wq, wj00, wj01, wj10, wj11, rW1, rb1, g1, be1, rW2,
        rb2, g2, be2, W3_00, b3_00, W3_01, b3_01, W3_10, b3_10, W3_11, b3_11,
        out, ssum, E);
    norm_kernel<<<gp, TPB, 0, stream>>>(out, v, ssum, E);
}